// Round 4
// baseline (92.161 us; speedup 1.0000x reference)
//
#include <hip/hip_runtime.h>

#define B   16
#define C1  256          // channels per input
#define C2  512          // total channels after concat
#define HW  4096         // 64*64 pixels per channel
#define NSPLIT 16        // tail channel-splits per batch

typedef float vf4 __attribute__((ext_vector_type(4)));

__device__ __forceinline__ const vf4* chan_base(
    const float* __restrict__ x1, const float* __restrict__ x2, int b, int c)
{
    return (const vf4*)((c < C1) ? (x1 + (size_t)(b * C1 + c) * HW)
                                 : (x2 + (size_t)(b * C1 + (c - C1)) * HW));
}

// ---------------------------------------------------------------------------
// Kernel 1: per-(batch, channel) global sum over H*W  -> pooled[B*C2]
// One WAVE per channel: 64 lanes x 16 float4. No LDS, no sync.
// ---------------------------------------------------------------------------
__global__ __launch_bounds__(256) void pool_kernel(
    const float* __restrict__ x1, const float* __restrict__ x2,
    float* __restrict__ pooled)
{
    int t    = threadIdx.x;
    int wid  = t >> 6;
    int lane = t & 63;
    int bc   = blockIdx.x * 4 + wid;   // grid = 512 -> 0..2047
    int b    = bc >> 9;
    int c    = bc & (C2 - 1);
    const vf4* p = chan_base(x1, x2, b, c);

    vf4 a0 = (vf4)(0.f), a1 = (vf4)(0.f), a2 = (vf4)(0.f), a3 = (vf4)(0.f);
    #pragma unroll
    for (int i = 0; i < 16; i += 4) {
        vf4 v0 = p[lane + (i + 0) * 64];
        vf4 v1 = p[lane + (i + 1) * 64];
        vf4 v2 = p[lane + (i + 2) * 64];
        vf4 v3 = p[lane + (i + 3) * 64];
        a0 += v0; a1 += v1; a2 += v2; a3 += v3;
    }
    vf4 a = (a0 + a1) + (a2 + a3);
    float s = (a.x + a.y) + (a.z + a.w);

    #pragma unroll
    for (int off = 32; off > 0; off >>= 1)
        s += __shfl_down(s, off, 64);

    if (lane == 0)
        pooled[bc] = s;
}

// ---------------------------------------------------------------------------
// Kernel 2: per-batch stable descending rank-sort of pooled values.
// Also zeros out[b, k-1, :] so the gather tail can atomicAdd into it.
// ---------------------------------------------------------------------------
__global__ __launch_bounds__(512) void sort_kernel(
    const float* __restrict__ pooled, int* __restrict__ idx,
    float* __restrict__ out, int k)
{
    int b = blockIdx.x;
    int t = threadIdx.x;            // 512 threads = one per channel

    // zero the fold-target channel (1024 float4 = 16 KB)
    vf4* oz = (vf4*)(out + (size_t)(b * k + (k - 1)) * HW);
    oz[t]       = (vf4)(0.f);
    oz[t + 512] = (vf4)(0.f);

    __shared__ float sp[C2];
    float v = pooled[b * C2 + t];
    sp[t] = v;
    __syncthreads();
    int rank = 0;
    for (int j = 0; j < C2; ++j) {
        float u = sp[j];
        rank += (u > v) || (u == v && j < t);
    }
    idx[b * C2 + rank] = t;
}

// ---------------------------------------------------------------------------
// Kernel 3: gather channels in sorted order; fold tail sum into channel k-1.
// Grid: [0, B*NSPLIT)        -> tail-partial blocks (atomicAdd into k-1)
//       [B*NSPLIT, +B*(k-1)) -> plain copy blocks (channels 0..k-2)
// ---------------------------------------------------------------------------
__global__ __launch_bounds__(256) void gather_kernel(
    const float* __restrict__ x1, const float* __restrict__ x2,
    const int* __restrict__ idx, float* __restrict__ out, int k)
{
    int t   = threadIdx.x;
    int bid = blockIdx.x;
    int ntail = B * NSPLIT;

    if (bid < ntail) {
        // ---- tail-partial block: channels ranked k-1+s, k-1+s+16, ...
        int b = bid / NSPLIT;
        int s = bid % NSPLIT;
        vf4 a0 = (vf4)(0.f), a1 = (vf4)(0.f), a2 = (vf4)(0.f), a3 = (vf4)(0.f);
        for (int j = (k - 1) + s; j < C2; j += NSPLIT) {
            int c = idx[b * C2 + j];
            const vf4* p = chan_base(x1, x2, b, c);
            a0 += p[t];
            a1 += p[t + 256];
            a2 += p[t + 512];
            a3 += p[t + 768];
        }
        float* o = out + (size_t)(b * k + (k - 1)) * HW;
        float* o0 = o + 4 * t;
        float* o1 = o0 + 4 * 256;
        float* o2 = o0 + 4 * 512;
        float* o3 = o0 + 4 * 768;
        atomicAdd(o0 + 0, a0.x); atomicAdd(o0 + 1, a0.y);
        atomicAdd(o0 + 2, a0.z); atomicAdd(o0 + 3, a0.w);
        atomicAdd(o1 + 0, a1.x); atomicAdd(o1 + 1, a1.y);
        atomicAdd(o1 + 2, a1.z); atomicAdd(o1 + 3, a1.w);
        atomicAdd(o2 + 0, a2.x); atomicAdd(o2 + 1, a2.y);
        atomicAdd(o2 + 2, a2.z); atomicAdd(o2 + 3, a2.w);
        atomicAdd(o3 + 0, a3.x); atomicAdd(o3 + 1, a3.y);
        atomicAdd(o3 + 2, a3.z); atomicAdd(o3 + 3, a3.w);
    } else {
        // ---- plain copy block: out[b, o, :] = x[b, idx[b,o], :]
        int cb = bid - ntail;                  // 0 .. B*(k-1)-1
        int b  = cb / (k - 1);
        int o  = cb % (k - 1);
        int c  = idx[b * C2 + o];
        const vf4* src = chan_base(x1, x2, b, c);
        vf4* dst = (vf4*)(out + (size_t)(b * k + o) * HW);
        #pragma unroll
        for (int i = 0; i < 4; ++i)
            dst[t + i * 256] = src[t + i * 256];
    }
}

// ---------------------------------------------------------------------------
extern "C" void kernel_launch(void* const* d_in, const int* in_sizes, int n_in,
                              void* d_out, int out_size, void* d_ws, size_t ws_size,
                              hipStream_t stream)
{
    const float* x1 = (const float*)d_in[0];
    const float* x2 = (const float*)d_in[1];
    float* out = (float*)d_out;

    int k = out_size / (B * HW);               // = 256

    float* pooled = (float*)d_ws;              // B*C2 floats = 32 KB
    int*   idx    = (int*)((char*)d_ws + B * C2 * sizeof(float)); // 32 KB

    pool_kernel<<<(B * C2) / 4, 256, 0, stream>>>(x1, x2, pooled);
    sort_kernel<<<B, 512, 0, stream>>>(pooled, idx, out, k);

    int ngather = B * NSPLIT + B * (k - 1);
    gather_kernel<<<ngather, 256, 0, stream>>>(x1, x2, idx, out, k);
}

// Round 5
// 70.797 us; speedup vs baseline: 1.3018x; 1.3018x over previous
//
#include <hip/hip_runtime.h>

#define B   16
#define C1  256          // channels per input
#define C2  512          // total channels after concat
#define HW  4096         // 64*64 pixels per channel
#define TCHUNK 32        // tail pixel-chunks per batch (128 pixels each)
#define CPB 8            // channels copied per copy-block

typedef float vf4 __attribute__((ext_vector_type(4)));

__device__ __forceinline__ const vf4* chan_base(
    const float* __restrict__ x1, const float* __restrict__ x2, int b, int c)
{
    return (const vf4*)((c < C1) ? (x1 + (size_t)(b * C1 + c) * HW)
                                 : (x2 + (size_t)(b * C1 + (c - C1)) * HW));
}

// ---------------------------------------------------------------------------
// Kernel 1: per-(batch, channel) global sum over H*W  -> pooled[B*C2]
// One WAVE per channel: 64 lanes x 16 float4. No LDS, no sync.
// ---------------------------------------------------------------------------
__global__ __launch_bounds__(256) void pool_kernel(
    const float* __restrict__ x1, const float* __restrict__ x2,
    float* __restrict__ pooled)
{
    int t    = threadIdx.x;
    int wid  = t >> 6;
    int lane = t & 63;
    int bc   = blockIdx.x * 4 + wid;   // grid = 512 -> 0..2047
    int b    = bc >> 9;
    int c    = bc & (C2 - 1);
    const vf4* p = chan_base(x1, x2, b, c);

    vf4 a0 = (vf4)(0.f), a1 = (vf4)(0.f), a2 = (vf4)(0.f), a3 = (vf4)(0.f);
    #pragma unroll
    for (int i = 0; i < 16; i += 4) {
        vf4 v0 = p[lane + (i + 0) * 64];
        vf4 v1 = p[lane + (i + 1) * 64];
        vf4 v2 = p[lane + (i + 2) * 64];
        vf4 v3 = p[lane + (i + 3) * 64];
        a0 += v0; a1 += v1; a2 += v2; a3 += v3;
    }
    vf4 a = (a0 + a1) + (a2 + a3);
    float s = (a.x + a.y) + (a.z + a.w);

    #pragma unroll
    for (int off = 32; off > 0; off >>= 1)
        s += __shfl_down(s, off, 64);

    if (lane == 0)
        pooled[bc] = s;
}

// ---------------------------------------------------------------------------
// Kernel 2: per-batch stable descending rank-sort of pooled values.
// ---------------------------------------------------------------------------
__global__ __launch_bounds__(512) void sort_kernel(
    const float* __restrict__ pooled, int* __restrict__ idx)
{
    int b = blockIdx.x;
    int t = threadIdx.x;            // 512 threads = one per channel
    __shared__ float sp[C2];
    float v = pooled[b * C2 + t];
    sp[t] = v;
    __syncthreads();
    int rank = 0;
    for (int j = 0; j < C2; ++j) {
        float u = sp[j];
        rank += (u > v) || (u == v && j < t);
    }
    idx[b * C2 + rank] = t;
}

// ---------------------------------------------------------------------------
// Kernel 3: gather channels in sorted order; fold tail sum into channel k-1.
// Grid: [0, B*TCHUNK)    tail blocks: each owns 128 pixels exclusively,
//                        sums all 257 tail channels (8 groups x 32 f4-slots,
//                        4-way ILP), LDS-reduces, plain store. No atomics.
//       [B*TCHUNK, ...)  copy blocks: CPB channels each, unrolled so loads
//                        of the next channel overlap stores of the current.
// ---------------------------------------------------------------------------
__global__ __launch_bounds__(256) void gather_kernel(
    const float* __restrict__ x1, const float* __restrict__ x2,
    const int* __restrict__ idx, float* __restrict__ out, int k)
{
    int t   = threadIdx.x;
    int bid = blockIdx.x;
    int ntail = B * TCHUNK;

    if (bid < ntail) {
        // ---- tail block
        int b     = bid / TCHUNK;
        int chunk = bid % TCHUNK;
        int g     = t >> 5;          // channel group 0..7
        int slot  = t & 31;          // f4 slot within 128-pixel chunk
        int off   = chunk * 32 + slot;  // f4 index in channel
        int ntc   = C2 - (k - 1);    // 257 tail channels

        __shared__ int ch[C2];
        __shared__ vf4 red[8][32];
        for (int i = t; i < ntc; i += 256)
            ch[i] = idx[b * C2 + (k - 1) + i];
        __syncthreads();

        vf4 a0 = (vf4)(0.f), a1 = (vf4)(0.f), a2 = (vf4)(0.f), a3 = (vf4)(0.f);
        int j = g;
        for (; j + 24 < ntc; j += 32) {
            int c0 = ch[j], c1 = ch[j + 8], c2 = ch[j + 16], c3 = ch[j + 24];
            a0 += chan_base(x1, x2, b, c0)[off];
            a1 += chan_base(x1, x2, b, c1)[off];
            a2 += chan_base(x1, x2, b, c2)[off];
            a3 += chan_base(x1, x2, b, c3)[off];
        }
        for (; j < ntc; j += 8)
            a0 += chan_base(x1, x2, b, ch[j])[off];

        red[g][slot] = (a0 + a1) + (a2 + a3);
        __syncthreads();
        if (g == 0) {
            vf4 r = (vf4)(0.f);
            #pragma unroll
            for (int gg = 0; gg < 8; ++gg)
                r += red[gg][slot];
            vf4* o = (vf4*)(out + (size_t)(b * k + (k - 1)) * HW);
            o[off] = r;
        }
    } else {
        // ---- copy block: CPB channels
        int cb = bid - ntail;
        int nslots = B * (k - 1);
        int cc[CPB];
        #pragma unroll
        for (int i = 0; i < CPB; ++i) {
            int sl = cb * CPB + i;
            if (sl < nslots) {
                int b = sl / (k - 1);
                int o = sl % (k - 1);
                cc[i] = b * C2 + o;      // temp: slot of idx
            } else cc[i] = -1;
        }
        #pragma unroll
        for (int i = 0; i < CPB; ++i)
            if (cc[i] >= 0) cc[i] = idx[cc[i]] | ((cc[i] / C2) << 16); // pack b
        #pragma unroll
        for (int i = 0; i < CPB; ++i) {
            if (cc[i] < 0) continue;
            int b = cc[i] >> 16;
            int c = cc[i] & 0xFFFF;
            int sl = cb * CPB + i;
            int o  = sl % (k - 1);
            const vf4* src = chan_base(x1, x2, b, c);
            vf4* dst = (vf4*)(out + (size_t)(b * k + o) * HW);
            vf4 v0 = src[t], v1 = src[t + 256], v2 = src[t + 512], v3 = src[t + 768];
            dst[t] = v0; dst[t + 256] = v1; dst[t + 512] = v2; dst[t + 768] = v3;
        }
    }
}

// ---------------------------------------------------------------------------
extern "C" void kernel_launch(void* const* d_in, const int* in_sizes, int n_in,
                              void* d_out, int out_size, void* d_ws, size_t ws_size,
                              hipStream_t stream)
{
    const float* x1 = (const float*)d_in[0];
    const float* x2 = (const float*)d_in[1];
    float* out = (float*)d_out;

    int k = out_size / (B * HW);               // = 256

    float* pooled = (float*)d_ws;              // B*C2 floats = 32 KB
    int*   idx    = (int*)((char*)d_ws + B * C2 * sizeof(float)); // 32 KB

    pool_kernel<<<(B * C2) / 4, 256, 0, stream>>>(x1, x2, pooled);
    sort_kernel<<<B, 512, 0, stream>>>(pooled, idx);

    int ncopy = (B * (k - 1) + CPB - 1) / CPB;     // 510
    gather_kernel<<<B * TCHUNK + ncopy, 256, 0, stream>>>(x1, x2, idx, out, k);
}